// Round 4
// baseline (213.629 us; speedup 1.0000x reference)
//
#include <hip/hip_runtime.h>
#include <hip/hip_bf16.h>

typedef unsigned short u16;
typedef __bf16 bf16x8 __attribute__((ext_vector_type(8)));
typedef __bf16 bf16x4 __attribute__((ext_vector_type(4)));
typedef float f32x4 __attribute__((ext_vector_type(4)));
typedef unsigned int uint32x2 __attribute__((ext_vector_type(2)));

#define MFMA16(a, b, c) __builtin_amdgcn_mfma_f32_16x16x32_bf16(a, b, c, 0, 0, 0)

// exp(z/8) = exp2(z * log2(e)/8); folded into fkT at projection time.
#define FK_SCALE 0.1803368801111204f  // 0.125 * log2(e)

#define NSPLIT 4
#define CH 128  // l processed per barrier-iteration

// ---------------------------------------------------------------------------
// Projections: fkeys/fvals/hkeys = W @ src + b, output bf16.
//   fkT[b][l][64] (k contiguous, PRE-SCALED) / hkT[b][q][64] / fv[b][64][l]
// grid: (16, B, 6)  z = proj*2 + khalf (32 k-rows per block).
// Chunked + software-pipelined x loads; acc[32]+xc[8]+xn[8] -> no spill.
// ---------------------------------------------------------------------------
__global__ __launch_bounds__(256) void proj_kernel(
    const float* __restrict__ field, const float* __restrict__ query,
    const float* __restrict__ Wfk, const float* __restrict__ bfk,
    const float* __restrict__ Wfv, const float* __restrict__ bfv,
    const float* __restrict__ Wqk, const float* __restrict__ bqk,
    u16* __restrict__ fkT, u16* __restrict__ fvp, u16* __restrict__ hkT) {
  const int l = blockIdx.x * 256 + threadIdx.x;
  const int b = blockIdx.y;
  const int z = blockIdx.z;
  const int proj = z >> 1;        // 0=fk, 1=fv, 2=hk
  const int k0 = (z & 1) * 32;

  const float* src  = (proj == 2) ? query : field;
  const float* W    = (proj == 0) ? Wfk : (proj == 1) ? Wfv : Wqk;
  const float* bias = (proj == 0) ? bfk : (proj == 1) ? bfv : bqk;

  const float* sp = src + (size_t)b * 128 * 4096 + l;

  float acc[32];
#pragma unroll
  for (int i = 0; i < 32; ++i) acc[i] = bias[k0 + i];

  float xc[8];
#pragma unroll
  for (int j = 0; j < 8; ++j) xc[j] = sp[(size_t)j * 4096];

#pragma unroll 1
  for (int fc = 0; fc < 128; fc += 8) {
    float xn[8];
    if (fc + 8 < 128) {
#pragma unroll
      for (int j = 0; j < 8; ++j) xn[j] = sp[(size_t)(fc + 8 + j) * 4096];
    }
#pragma unroll
    for (int i = 0; i < 32; ++i) {
      const float* wr = W + (size_t)(k0 + i) * 128 + fc;
      float a = acc[i];
#pragma unroll
      for (int j = 0; j < 8; ++j) a = fmaf(wr[j], xc[j], a);
      acc[i] = a;
    }
#pragma unroll
    for (int j = 0; j < 8; ++j) xc[j] = xn[j];
  }

  if (proj == 1) {
#pragma unroll
    for (int i = 0; i < 32; ++i) {
      __bf16 h = (__bf16)acc[i];
      fvp[((size_t)(b * 64 + k0 + i)) * 4096 + l] = __builtin_bit_cast(u16, h);
    }
  } else {
    const float cs = (proj == 0) ? FK_SCALE : 1.0f;
    u16* dst = ((proj == 0) ? fkT : hkT) + ((size_t)(b * 4096 + l)) * 64 + k0;
#pragma unroll
    for (int g = 0; g < 4; ++g) {
      bf16x8 o;
#pragma unroll
      for (int j = 0; j < 8; ++j) o[j] = (__bf16)(acc[g * 8 + j] * cs);
      *reinterpret_cast<bf16x8*>(dst + g * 8) = o;
    }
  }
}

// ---------------------------------------------------------------------------
// Attention: per (qtile 64, b, l-split 1024). 8 iterations of 128 l.
//   Per wave per iter: 2 S-strips (16 l each) -> 16 S-MFMA, exp2 -> bf16 ->
//   LDS P_T[q][128l] (16B-block XOR swizzle, dbuf), ONE barrier, then
//   PV 16 MFMA (K=128) + 4 denom MFMA (ones-vector A).  hk frags persistent;
//   fv frags issued at iter top, fk frags prefetched one iter ahead -> the
//   vmcnt drain at the barrier waits only on ~600-cycle-old loads.
// ---------------------------------------------------------------------------
__global__ __launch_bounds__(256, 3) void attn_kernel(
    const u16* __restrict__ fkT, const u16* __restrict__ hkT,
    const u16* __restrict__ fvp, float* __restrict__ Ynum,
    float* __restrict__ den) {
  constexpr int LL = 4096, DD = 64, NITER = (LL / NSPLIT) / CH;  // 8
  const int tid = threadIdx.x;
  const int w = tid >> 6;
  const int lane = tid & 63;
  const int q15 = lane & 15;
  const int quad = lane >> 4;
  const int qtile = blockIdx.x;
  const int b = blockIdx.y;
  const int split = blockIdx.z;
  const int q0 = qtile * 64;
  const int l0base = split * (LL / NSPLIT);
  const int sw = q15 & 7;  // row-derived XOR swizzle (16B-block granularity)

  __shared__ __align__(16) u16 sP[2][64 * CH];  // 2 x 16 KB, P_T[q][l]

  // hk B-fragments, persistent: B[k][n=q], n=lane&15, k=quad*8+j
  bf16x8 hkf[4][2];
#pragma unroll
  for (int j = 0; j < 4; ++j)
#pragma unroll
    for (int ks = 0; ks < 2; ++ks)
      hkf[j][ks] = *reinterpret_cast<const bf16x8*>(
          hkT + ((size_t)(b * LL + q0 + j * 16 + q15)) * DD + ks * 32 + quad * 8);

  f32x4 Yacc[2][2];
#pragma unroll
  for (int mm = 0; mm < 2; ++mm)
#pragma unroll
    for (int nn = 0; nn < 2; ++nn) Yacc[mm][nn] = (f32x4){0.f, 0.f, 0.f, 0.f};
  f32x4 denAcc = (f32x4){0.f, 0.f, 0.f, 0.f};

  bf16x8 ones;
#pragma unroll
  for (int j = 0; j < 8; ++j) ones[j] = (__bf16)1.0f;

  const int m0y = (w & 1) * 32;   // v quadrant
  const int n0y = (w >> 1) * 32;  // q quadrant

  const u16* fkBase = fkT + ((size_t)(b * LL + w * 16 + q15)) * DD + quad * 8;
  const u16* fvB0 = fvp + ((size_t)(b * DD + m0y + q15)) * LL + quad * 8;
  const u16* fvB1 = fvB0 + (size_t)16 * LL;

  // preload fk fragments for it=0 (strip s covers l rows s*64 + w*16 + ..)
  bf16x8 fkf[2][2];
#pragma unroll
  for (int s = 0; s < 2; ++s)
#pragma unroll
    for (int ks = 0; ks < 2; ++ks)
      fkf[s][ks] = *reinterpret_cast<const bf16x8*>(
          fkBase + (size_t)(l0base + s * 64) * DD + ks * 32);

#pragma unroll 2
  for (int it = 0; it < NITER; ++it) {
    const int l0 = l0base + it * CH;
    u16* sPb = sP[it & 1];

    // --- issue this iter's PV A-fragments (consumed after the barrier) ---
    bf16x8 af[2][4];
#pragma unroll
    for (int ks = 0; ks < 4; ++ks) {
      af[0][ks] = *reinterpret_cast<const bf16x8*>(fvB0 + l0 + ks * 32);
      af[1][ks] = *reinterpret_cast<const bf16x8*>(fvB1 + l0 + ks * 32);
    }
    // --- prefetch next iteration's fk fragments ---
    bf16x8 fkn[2][2];
    if (it + 1 < NITER) {
#pragma unroll
      for (int s = 0; s < 2; ++s)
#pragma unroll
        for (int ks = 0; ks < 2; ++ks)
          fkn[s][ks] = *reinterpret_cast<const bf16x8*>(
              fkBase + (size_t)(l0 + CH + s * 64) * DD + ks * 32);
    }

    // --- S strips: MFMA -> exp2 -> swizzled LDS transpose ---
#pragma unroll
    for (int s = 0; s < 2; ++s) {
      f32x4 accS[4];
#pragma unroll
      for (int j = 0; j < 4; ++j) accS[j] = (f32x4){0.f, 0.f, 0.f, 0.f};
#pragma unroll
      for (int ks = 0; ks < 2; ++ks)
#pragma unroll
        for (int j = 0; j < 4; ++j)
          accS[j] = MFMA16(fkf[s][ks], hkf[j][ks], accS[j]);

      // logical l-offset = s*64 + w*16 + quad*4 + r; 16B-block swizzle
      const int coff = (((s * 8 + w * 2 + (quad >> 1)) ^ sw) << 3) + (quad & 1) * 4;
#pragma unroll
      for (int j = 0; j < 4; ++j) {
        bf16x4 pk;
#pragma unroll
        for (int r = 0; r < 4; ++r)
          pk[r] = (__bf16)__builtin_amdgcn_exp2f(accS[j][r]);
        *reinterpret_cast<uint32x2*>(&sPb[(j * 16 + q15) * CH + coff]) =
            __builtin_bit_cast(uint32x2, pk);
      }
    }
    __syncthreads();

    // --- PV: Y += fv . P  (K=128), denom via ones-vector MFMA ---
#pragma unroll
    for (int ks = 0; ks < 4; ++ks) {
      bf16x8 bfr[2];
#pragma unroll
      for (int nn = 0; nn < 2; ++nn)
        bfr[nn] = *reinterpret_cast<const bf16x8*>(
            &sPb[(n0y + nn * 16 + q15) * CH + (((ks * 4 + quad) ^ sw) << 3)]);
      denAcc = MFMA16(ones, bfr[w & 1], denAcc);
#pragma unroll
      for (int mm = 0; mm < 2; ++mm)
#pragma unroll
        for (int nn = 0; nn < 2; ++nn)
          Yacc[mm][nn] = MFMA16(af[mm][ks], bfr[nn], Yacc[mm][nn]);
    }

#pragma unroll
    for (int s = 0; s < 2; ++s)
#pragma unroll
      for (int ks = 0; ks < 2; ++ks) fkf[s][ks] = fkn[s][ks];
  }

  const size_t slot = ((size_t)split * 4 + b) * 64 + qtile;
  // denom: all 16 C-rows of denAcc are identical; quad0/r0 lanes hold it.
  // wave w owns q-range n0y + (w&1)*16 (matches its bfr[w&1] fragment).
  if (quad == 0) den[slot * 64 + n0y + (w & 1) * 16 + q15] = denAcc[0];

  float* Yo = Ynum + slot * 4096;
#pragma unroll
  for (int mm = 0; mm < 2; ++mm)
#pragma unroll
    for (int nn = 0; nn < 2; ++nn)
#pragma unroll
      for (int r = 0; r < 4; ++r) {
        const int v = m0y + mm * 16 + quad * 4 + r;
        const int ql = n0y + nn * 16 + q15;
        Yo[v * 64 + ql] = Yacc[mm][nn][r];
      }
}

// ---------------------------------------------------------------------------
// Combine the NSPLIT l-splits and normalize. out[b][v][q], 1M elements.
// ---------------------------------------------------------------------------
__global__ __launch_bounds__(256) void combine_kernel(
    const float* __restrict__ Yn, const float* __restrict__ dn,
    float* __restrict__ out) {
  const int idx = blockIdx.x * 256 + threadIdx.x;
  const int q = idx & 4095;
  const int v = (idx >> 12) & 63;
  const int b = idx >> 18;
  const int qt = q >> 6, ql = q & 63;
  float num = 0.f, d = 1e-16f;
#pragma unroll
  for (int s = 0; s < NSPLIT; ++s) {
    const size_t slot = ((size_t)s * 4 + b) * 64 + qt;
    num += Yn[slot * 4096 + v * 64 + ql];
    d += dn[slot * 64 + ql];
  }
  out[idx] = num / d;
}

extern "C" void kernel_launch(void* const* d_in, const int* in_sizes, int n_in,
                              void* d_out, int out_size, void* d_ws,
                              size_t ws_size, hipStream_t stream) {
  const float* field = (const float*)d_in[0];
  const float* query = (const float*)d_in[1];
  const float* Wfk = (const float*)d_in[2];
  const float* bfk = (const float*)d_in[3];
  const float* Wfv = (const float*)d_in[4];
  const float* bfv = (const float*)d_in[5];
  const float* Wqk = (const float*)d_in[6];
  const float* bqk = (const float*)d_in[7];
  float* out = (float*)d_out;

  char* ws = (char*)d_ws;
  u16* fkT = (u16*)(ws);                       // 2 MB   [B][L][64] bf16 (scaled)
  u16* hkT = (u16*)(ws + (2ull << 20));        // 2 MB   [B][L][64] bf16
  u16* fvp = (u16*)(ws + (4ull << 20));        // 2 MB   [B][64][L] bf16
  float* Ynum = (float*)(ws + (6ull << 20));   // 16 MB  [4][B][64qt][64v][64q]
  float* den = (float*)(ws + (22ull << 20));   // 256 KB [4][B][64qt][64q]

  proj_kernel<<<dim3(16, 4, 6), 256, 0, stream>>>(field, query, Wfk, bfk, Wfv,
                                                  bfv, Wqk, bqk, fkT, fvp, hkT);
  attn_kernel<<<dim3(64, 4, NSPLIT), 256, 0, stream>>>(fkT, hkT, fvp, Ynum, den);
  combine_kernel<<<dim3(4096), 256, 0, stream>>>(Ynum, den, out);
}

// Round 5
// 193.360 us; speedup vs baseline: 1.1048x; 1.1048x over previous
//
#include <hip/hip_runtime.h>
#include <hip/hip_bf16.h>

typedef unsigned short u16;
typedef __bf16 bf16x8 __attribute__((ext_vector_type(8)));
typedef __bf16 bf16x4 __attribute__((ext_vector_type(4)));
typedef float f32x4 __attribute__((ext_vector_type(4)));
typedef unsigned int uint32x2 __attribute__((ext_vector_type(2)));

#define MFMA16(a, b, c) __builtin_amdgcn_mfma_f32_16x16x32_bf16(a, b, c, 0, 0, 0)

// exp(z/8) = exp2(z * log2(e)/8); folded into fkT at projection time.
#define FK_SCALE 0.1803368801111204f  // 0.125 * log2(e)

#define NSPLIT 8

// ---------------------------------------------------------------------------
// Projections: fkeys/fvals/hkeys = W @ src + b, output bf16.
//   fkT[b][l][64] (k contiguous, PRE-SCALED) / hkT[b][q][64] / fv[b][64][l]
// grid: (16, B, 6)  z = proj*2 + khalf (32 k-rows per block).
// Chunked + software-pipelined x loads; acc[32]+xc[8]+xn[8] -> no spill.
// ---------------------------------------------------------------------------
__global__ __launch_bounds__(256) void proj_kernel(
    const float* __restrict__ field, const float* __restrict__ query,
    const float* __restrict__ Wfk, const float* __restrict__ bfk,
    const float* __restrict__ Wfv, const float* __restrict__ bfv,
    const float* __restrict__ Wqk, const float* __restrict__ bqk,
    u16* __restrict__ fkT, u16* __restrict__ fvp, u16* __restrict__ hkT) {
  const int l = blockIdx.x * 256 + threadIdx.x;
  const int b = blockIdx.y;
  const int z = blockIdx.z;
  const int proj = z >> 1;        // 0=fk, 1=fv, 2=hk
  const int k0 = (z & 1) * 32;

  const float* src  = (proj == 2) ? query : field;
  const float* W    = (proj == 0) ? Wfk : (proj == 1) ? Wfv : Wqk;
  const float* bias = (proj == 0) ? bfk : (proj == 1) ? bfv : bqk;

  const float* sp = src + (size_t)b * 128 * 4096 + l;

  float acc[32];
#pragma unroll
  for (int i = 0; i < 32; ++i) acc[i] = bias[k0 + i];

  float xc[8];
#pragma unroll
  for (int j = 0; j < 8; ++j) xc[j] = sp[(size_t)j * 4096];

#pragma unroll 1
  for (int fc = 0; fc < 128; fc += 8) {
    float xn[8];
    if (fc + 8 < 128) {
#pragma unroll
      for (int j = 0; j < 8; ++j) xn[j] = sp[(size_t)(fc + 8 + j) * 4096];
    }
#pragma unroll
    for (int i = 0; i < 32; ++i) {
      const float* wr = W + (size_t)(k0 + i) * 128 + fc;
      float a = acc[i];
#pragma unroll
      for (int j = 0; j < 8; ++j) a = fmaf(wr[j], xc[j], a);
      acc[i] = a;
    }
#pragma unroll
    for (int j = 0; j < 8; ++j) xc[j] = xn[j];
  }

  if (proj == 1) {
#pragma unroll
    for (int i = 0; i < 32; ++i) {
      __bf16 h = (__bf16)acc[i];
      fvp[((size_t)(b * 64 + k0 + i)) * 4096 + l] = __builtin_bit_cast(u16, h);
    }
  } else {
    const float cs = (proj == 0) ? FK_SCALE : 1.0f;
    u16* dst = ((proj == 0) ? fkT : hkT) + ((size_t)(b * 4096 + l)) * 64 + k0;
#pragma unroll
    for (int g = 0; g < 4; ++g) {
      bf16x8 o;
#pragma unroll
      for (int j = 0; j < 8; ++j) o[j] = (__bf16)(acc[g * 8 + j] * cs);
      *reinterpret_cast<bf16x8*>(dst + g * 8) = o;
    }
  }
}

// ---------------------------------------------------------------------------
// Attention, BARRIER-FREE: one wave per (32-q stripe, b, l-split of 512).
// Block = 64 threads = 1 wave; grid (128, 4, 8) = 4096 independent waves.
// Per 64-l chunk: S (4 strips x 16l x 32q, 16 MFMA) -> exp2 -> bf16 ->
// wave-PRIVATE LDS P_T[32q][64l] (16B XOR swizzle, dbuf, conflict-free) ->
// PV 16 MFMA + 4 ones-MFMA denominator. No __syncthreads anywhere; only
// intra-wave lgkmcnt waits. hk frags persistent; fk/fv issued at chunk top.
// ---------------------------------------------------------------------------
__global__ __launch_bounds__(64, 3) void attn_kernel(
    const u16* __restrict__ fkT, const u16* __restrict__ hkT,
    const u16* __restrict__ fvp, float* __restrict__ Ynum,
    float* __restrict__ den) {
  constexpr int LL = 4096, DD = 64, CH = 64, NITER = (LL / NSPLIT) / CH;  // 8
  const int lane = threadIdx.x;
  const int q15 = lane & 15;
  const int quad = lane >> 4;
  const int qblk = blockIdx.x;          // 0..127, 32 q each
  const int b = blockIdx.y;
  const int split = blockIdx.z;
  const int q0 = qblk * 32;
  const int l0base = split * (LL / NSPLIT);
  const int sw = q15 & 7;               // XOR swizzle key (= row & 7)

  __shared__ __align__(16) char sP[2][32 * 128];  // 2 x 4KB, P_T[q32][l64]

  // hk B-frags, persistent: B[k][n=q], n=q15, k=quad*8+j'
  bf16x8 hkf[2][2];
#pragma unroll
  for (int j = 0; j < 2; ++j)
#pragma unroll
    for (int ks = 0; ks < 2; ++ks)
      hkf[j][ks] = *reinterpret_cast<const bf16x8*>(
          hkT + ((size_t)(b * LL + q0 + j * 16 + q15)) * DD + ks * 32 + quad * 8);

  bf16x8 ones;
#pragma unroll
  for (int j = 0; j < 8; ++j) ones[j] = (__bf16)1.0f;

  f32x4 Yacc[4][2];
#pragma unroll
  for (int mm = 0; mm < 4; ++mm)
#pragma unroll
    for (int nn = 0; nn < 2; ++nn) Yacc[mm][nn] = (f32x4){0.f, 0.f, 0.f, 0.f};
  f32x4 denAcc[2] = {(f32x4){0.f, 0.f, 0.f, 0.f}, (f32x4){0.f, 0.f, 0.f, 0.f}};

  const u16* fkBase = fkT + ((size_t)(b * LL + q15)) * DD + quad * 8;
  const u16* fvBase = fvp + ((size_t)(b * DD + q15)) * LL + quad * 8;

#pragma unroll 2
  for (int it = 0; it < NITER; ++it) {
    const int l0 = l0base + it * CH;
    char* sPb = sP[it & 1];

    // --- issue all global loads for this chunk up front ---
    bf16x8 fkf[4][2];  // strip s: A[m=l = l0+s*16+q15][k]
#pragma unroll
    for (int s = 0; s < 4; ++s)
#pragma unroll
      for (int ks = 0; ks < 2; ++ks)
        fkf[s][ks] = *reinterpret_cast<const bf16x8*>(
            fkBase + (size_t)(l0 + s * 16) * DD + ks * 32);
    bf16x8 af[4][2];   // A[m=v = mm*16+q15][k=l]
#pragma unroll
    for (int mm = 0; mm < 4; ++mm)
#pragma unroll
      for (int ks = 0; ks < 2; ++ks)
        af[mm][ks] = *reinterpret_cast<const bf16x8*>(
            fvBase + (size_t)(mm * 16) * LL + l0 + ks * 32);

    // --- S strips: MFMA -> exp2 -> swizzled wave-private LDS transpose ---
#pragma unroll
    for (int s = 0; s < 4; ++s) {
      f32x4 accS[2];
#pragma unroll
      for (int j = 0; j < 2; ++j) accS[j] = (f32x4){0.f, 0.f, 0.f, 0.f};
#pragma unroll
      for (int ks = 0; ks < 2; ++ks)
#pragma unroll
        for (int j = 0; j < 2; ++j)
          accS[j] = MFMA16(fkf[s][ks], hkf[j][ks], accS[j]);

      // C/D: col q = j*16+q15 (row of P_T), row l = s*16+quad*4+r (col).
      // Unswizzled 16B-block of l-cols = 2s + (quad>>1); XOR with row&7.
      const int boff =
          (((s * 2 + (quad >> 1)) ^ sw) << 4) + (quad & 1) * 8;
#pragma unroll
      for (int j = 0; j < 2; ++j) {
        bf16x4 pk;
#pragma unroll
        for (int r = 0; r < 4; ++r)
          pk[r] = (__bf16)__builtin_amdgcn_exp2f(accS[j][r]);
        *reinterpret_cast<uint32x2*>(sPb + (j * 16 + q15) * 128 + boff) =
            __builtin_bit_cast(uint32x2, pk);
      }
    }

    // --- PV: B-frag rows q=nn*16+q15, k=l=ks*32+quad*8+j' (one 16B blk) ---
#pragma unroll
    for (int ks = 0; ks < 2; ++ks) {
      bf16x8 bfr[2];
#pragma unroll
      for (int nn = 0; nn < 2; ++nn)
        bfr[nn] = *reinterpret_cast<const bf16x8*>(
            sPb + (nn * 16 + q15) * 128 + (((ks * 4 + quad) ^ sw) << 4));
#pragma unroll
      for (int nn = 0; nn < 2; ++nn)
        denAcc[nn] = MFMA16(ones, bfr[nn], denAcc[nn]);
#pragma unroll
      for (int mm = 0; mm < 4; ++mm)
#pragma unroll
        for (int nn = 0; nn < 2; ++nn)
          Yacc[mm][nn] = MFMA16(af[mm][ks], bfr[nn], Yacc[mm][nn]);
    }
  }

  // --- epilogue: unnormalized Y + denom partials ---
  const size_t slot = ((size_t)split * 4 + b) * 128 + qblk;
  if (quad == 0) {
#pragma unroll
    for (int nn = 0; nn < 2; ++nn)
      den[slot * 32 + nn * 16 + q15] = denAcc[nn][0];  // all C rows equal
  }
  float* Yo = Ynum + slot * (64 * 32);
#pragma unroll
  for (int mm = 0; mm < 4; ++mm)
#pragma unroll
    for (int nn = 0; nn < 2; ++nn)
#pragma unroll
      for (int r = 0; r < 4; ++r)
        Yo[(mm * 16 + quad * 4 + r) * 32 + nn * 16 + q15] = Yacc[mm][nn][r];
}

// ---------------------------------------------------------------------------
// Combine the NSPLIT l-splits and normalize. out[b][v][q], 1M elements.
// Ynum [s][b][qblk128][v64][q32], den [s][b][qblk128][q32].
// ---------------------------------------------------------------------------
__global__ __launch_bounds__(256) void combine_kernel(
    const float* __restrict__ Yn, const float* __restrict__ dn,
    float* __restrict__ out) {
  const int idx = blockIdx.x * 256 + threadIdx.x;
  const int q = idx & 4095;
  const int v = (idx >> 12) & 63;
  const int b = idx >> 18;
  const int qb = q >> 5, qq = q & 31;
  float num = 0.f, d = 1e-16f;
#pragma unroll
  for (int s = 0; s < NSPLIT; ++s) {
    const size_t slot = ((size_t)s * 4 + b) * 128 + qb;
    num += Yn[slot * 2048 + v * 32 + qq];
    d += dn[slot * 32 + qq];
  }
  out[idx] = num / d;
}

extern "C" void kernel_launch(void* const* d_in, const int* in_sizes, int n_in,
                              void* d_out, int out_size, void* d_ws,
                              size_t ws_size, hipStream_t stream) {
  const float* field = (const float*)d_in[0];
  const float* query = (const float*)d_in[1];
  const float* Wfk = (const float*)d_in[2];
  const float* bfk = (const float*)d_in[3];
  const float* Wfv = (const float*)d_in[4];
  const float* bfv = (const float*)d_in[5];
  const float* Wqk = (const float*)d_in[6];
  const float* bqk = (const float*)d_in[7];
  float* out = (float*)d_out;

  char* ws = (char*)d_ws;
  u16* fkT = (u16*)(ws);                       // 2 MB   [B][L][64] bf16 (scaled)
  u16* hkT = (u16*)(ws + (2ull << 20));        // 2 MB   [B][L][64] bf16
  u16* fvp = (u16*)(ws + (4ull << 20));        // 2 MB   [B][64][L] bf16
  float* Ynum = (float*)(ws + (6ull << 20));   // 32 MB  [8][B][128qb][64v][32q]
  float* den = (float*)(ws + (38ull << 20));   // 512 KB [8][B][128qb][32q]

  proj_kernel<<<dim3(16, 4, 6), 256, 0, stream>>>(field, query, Wfk, bfk, Wfv,
                                                  bfv, Wqk, bqk, fkT, fvp, hkT);
  attn_kernel<<<dim3(128, 4, NSPLIT), 64, 0, stream>>>(fkT, hkT, fvp, Ynum, den);
  combine_kernel<<<dim3(4096), 256, 0, stream>>>(Ynum, den, out);
}

// Round 6
// 171.854 us; speedup vs baseline: 1.2431x; 1.1251x over previous
//
#include <hip/hip_runtime.h>
#include <hip/hip_bf16.h>

typedef unsigned short u16;
typedef __bf16 bf16x8 __attribute__((ext_vector_type(8)));
typedef __bf16 bf16x4 __attribute__((ext_vector_type(4)));
typedef float f32x4 __attribute__((ext_vector_type(4)));
typedef unsigned int uint32x2 __attribute__((ext_vector_type(2)));

#define MFMA16(a, b, c) __builtin_amdgcn_mfma_f32_16x16x32_bf16(a, b, c, 0, 0, 0)

// exp(z/8) = exp2(z * log2(e)/8); folded into fkT at projection time.
#define FK_SCALE 0.1803368801111204f  // 0.125 * log2(e)

#define NSPLIT 8

// ---------------------------------------------------------------------------
// Projections: fkeys/fvals/hkeys = W @ src + b, output bf16.
//   fkT[b][l][64] (k contiguous, PRE-SCALED) / hkT[b][q][64] / fv[b][64][l]
// grid: (16, B, 12)  z = proj*4 + kquarter (16 k-rows per block -> 768 blocks,
// 3 waves/SIMD). Software-pipelined x loads; acc[16]+xc[8]+xn[8], no spill.
// ---------------------------------------------------------------------------
__global__ __launch_bounds__(256) void proj_kernel(
    const float* __restrict__ field, const float* __restrict__ query,
    const float* __restrict__ Wfk, const float* __restrict__ bfk,
    const float* __restrict__ Wfv, const float* __restrict__ bfv,
    const float* __restrict__ Wqk, const float* __restrict__ bqk,
    u16* __restrict__ fkT, u16* __restrict__ fvp, u16* __restrict__ hkT) {
  const int l = blockIdx.x * 256 + threadIdx.x;
  const int b = blockIdx.y;
  const int z = blockIdx.z;
  const int proj = z >> 2;        // 0=fk, 1=fv, 2=hk
  const int k0 = (z & 3) * 16;

  const float* src  = (proj == 2) ? query : field;
  const float* W    = (proj == 0) ? Wfk : (proj == 1) ? Wfv : Wqk;
  const float* bias = (proj == 0) ? bfk : (proj == 1) ? bfv : bqk;

  const float* sp = src + (size_t)b * 128 * 4096 + l;

  float acc[16];
#pragma unroll
  for (int i = 0; i < 16; ++i) acc[i] = bias[k0 + i];

  float xc[8];
#pragma unroll
  for (int j = 0; j < 8; ++j) xc[j] = sp[(size_t)j * 4096];

#pragma unroll 1
  for (int fc = 0; fc < 128; fc += 8) {
    float xn[8];
    if (fc + 8 < 128) {
#pragma unroll
      for (int j = 0; j < 8; ++j) xn[j] = sp[(size_t)(fc + 8 + j) * 4096];
    }
#pragma unroll
    for (int i = 0; i < 16; ++i) {
      const float* wr = W + (size_t)(k0 + i) * 128 + fc;
      float a = acc[i];
#pragma unroll
      for (int j = 0; j < 8; ++j) a = fmaf(wr[j], xc[j], a);
      acc[i] = a;
    }
#pragma unroll
    for (int j = 0; j < 8; ++j) xc[j] = xn[j];
  }

  if (proj == 1) {
#pragma unroll
    for (int i = 0; i < 16; ++i) {
      __bf16 h = (__bf16)acc[i];
      fvp[((size_t)(b * 64 + k0 + i)) * 4096 + l] = __builtin_bit_cast(u16, h);
    }
  } else {
    const float cs = (proj == 0) ? FK_SCALE : 1.0f;
    u16* dst = ((proj == 0) ? fkT : hkT) + ((size_t)(b * 4096 + l)) * 64 + k0;
#pragma unroll
    for (int g = 0; g < 2; ++g) {
      bf16x8 o;
#pragma unroll
      for (int j = 0; j < 8; ++j) o[j] = (__bf16)(acc[g * 8 + j] * cs);
      *reinterpret_cast<bf16x8*>(dst + g * 8) = o;
    }
  }
}

// ---------------------------------------------------------------------------
// Attention, barrier-free + CROSS-CHUNK PIPELINED. One wave per (32-q stripe,
// b, l-split of 512); grid (128, 4, 8) = 4096 independent waves.
// Steady state per 64-l chunk it:
//   ds_read P(it-1) [prev buf] ; S-MFMA(it) ; prefetch fk(it+1) ;
//   exp2 -> pack -> ds_write buf[it&1] ; PV-MFMA(it-1) ; load fv(it).
// PV never waits on data written this iteration -> LDS round-trip off the
// critical path. LDS layout is READ-ORDER LANE-LINEAR:
//   P[l][q] at (l>>5)*2048 + (q>>4)*1024 + (((l>>3)&3)*16 + (q&15))*16 + (l&7)*2
// so PV reads are contiguous 16B/lane (zero bank conflicts by construction);
// S-phase writes are one b64 of 4 adjacent bf16 per (s,jj) tile.
// ---------------------------------------------------------------------------
__global__ __launch_bounds__(64, 3) void attn_kernel(
    const u16* __restrict__ fkT, const u16* __restrict__ hkT,
    const u16* __restrict__ fvp, float* __restrict__ Ynum,
    float* __restrict__ den) {
  constexpr int LL = 4096, DD = 64, CH = 64, NITER = (LL / NSPLIT) / CH;  // 8
  const int lane = threadIdx.x;
  const int q15 = lane & 15;
  const int quad = lane >> 4;
  const int qblk = blockIdx.x;          // 0..127, 32 q each
  const int b = blockIdx.y;
  const int split = blockIdx.z;
  const int q0 = qblk * 32;
  const int l0base = split * (LL / NSPLIT);

  __shared__ __align__(16) char sP[2][4096];  // 2 x 4KB, read-order layout

  // hk B-frags, persistent: B[k][n=q], n=q15, k=quad*8+j'
  bf16x8 hkf[2][2];
#pragma unroll
  for (int j = 0; j < 2; ++j)
#pragma unroll
    for (int ks = 0; ks < 2; ++ks)
      hkf[j][ks] = *reinterpret_cast<const bf16x8*>(
          hkT + ((size_t)(b * LL + q0 + j * 16 + q15)) * DD + ks * 32 + quad * 8);

  bf16x8 ones;
#pragma unroll
  for (int j = 0; j < 8; ++j) ones[j] = (__bf16)1.0f;

  f32x4 Yacc[4][2];
#pragma unroll
  for (int mm = 0; mm < 4; ++mm)
#pragma unroll
    for (int nn = 0; nn < 2; ++nn) Yacc[mm][nn] = (f32x4){0.f, 0.f, 0.f, 0.f};
  f32x4 denAcc[2] = {(f32x4){0.f, 0.f, 0.f, 0.f}, (f32x4){0.f, 0.f, 0.f, 0.f}};

  const u16* fkBase = fkT + ((size_t)(b * LL + q15)) * DD + quad * 8;
  const u16* fvBase = fvp + ((size_t)(b * DD + q15)) * LL + quad * 8;

  // write offset pieces (lane-constant): full = (s>>1)*2048 + (s&1)*512
  //   + jj*1024 + wbase ; read: (ks*2+nn)*1024 + lane*16
  const int wbase = (quad >> 1) * 256 + q15 * 16 + (quad & 1) * 8;
  const int rbase = lane * 16;

  bf16x8 fkf[4][2];  // fk(it):  A[m=l][k],  strip s -> l = l0+s*16+q15
  bf16x8 af[4][2];   // fv(it-1) at PV time: A[m=v=mm*16+q15][k=l]

  auto loadFK = [&](int l0) {
#pragma unroll
    for (int s = 0; s < 4; ++s)
#pragma unroll
      for (int ks = 0; ks < 2; ++ks)
        fkf[s][ks] = *reinterpret_cast<const bf16x8*>(
            fkBase + (size_t)(l0 + s * 16) * DD + ks * 32);
  };
  auto loadAF = [&](int l0) {
#pragma unroll
    for (int mm = 0; mm < 4; ++mm)
#pragma unroll
      for (int ks = 0; ks < 2; ++ks)
        af[mm][ks] = *reinterpret_cast<const bf16x8*>(
            fvBase + (size_t)(mm * 16) * LL + l0 + ks * 32);
  };
  auto Sphase = [&](char* sPb) {
#pragma unroll
    for (int s = 0; s < 4; ++s) {
      f32x4 accS[2] = {(f32x4){0.f, 0.f, 0.f, 0.f}, (f32x4){0.f, 0.f, 0.f, 0.f}};
#pragma unroll
      for (int ks = 0; ks < 2; ++ks)
#pragma unroll
        for (int jj = 0; jj < 2; ++jj)
          accS[jj] = MFMA16(fkf[s][ks], hkf[jj][ks], accS[jj]);
      char* wp = sPb + (s >> 1) * 2048 + (s & 1) * 512 + wbase;
#pragma unroll
      for (int jj = 0; jj < 2; ++jj) {
        bf16x4 pk;
#pragma unroll
        for (int r = 0; r < 4; ++r)
          pk[r] = (__bf16)__builtin_amdgcn_exp2f(accS[jj][r]);
        *reinterpret_cast<uint32x2*>(wp + jj * 1024) =
            __builtin_bit_cast(uint32x2, pk);
      }
    }
  };
  auto PVphase = [&](const char* sPr) {
#pragma unroll
    for (int ks = 0; ks < 2; ++ks) {
      bf16x8 bfr0 = *reinterpret_cast<const bf16x8*>(sPr + ks * 2048 + rbase);
      bf16x8 bfr1 =
          *reinterpret_cast<const bf16x8*>(sPr + ks * 2048 + 1024 + rbase);
      denAcc[0] = MFMA16(ones, bfr0, denAcc[0]);
      denAcc[1] = MFMA16(ones, bfr1, denAcc[1]);
#pragma unroll
      for (int mm = 0; mm < 4; ++mm) {
        Yacc[mm][0] = MFMA16(af[mm][ks], bfr0, Yacc[mm][0]);
        Yacc[mm][1] = MFMA16(af[mm][ks], bfr1, Yacc[mm][1]);
      }
    }
  };

  // --- prologue: chunk 0's S into buf0 ---
  loadFK(l0base);
  loadAF(l0base);
  Sphase(sP[0]);
  loadFK(l0base + CH);  // fk(1)

  // --- steady state ---
#pragma unroll 2
  for (int it = 1; it < NITER; ++it) {
    const int l0 = l0base + it * CH;
    char* sPb = sP[it & 1];
    const char* sPr = sP[(it - 1) & 1];

    Sphase(sPb);                       // S(it): uses fkf = fk(it)
    if (it + 1 < NITER) loadFK(l0 + CH);  // prefetch fk(it+1)
    PVphase(sPr);                      // PV(it-1): af = fv(it-1), old buffer
    loadAF(l0);                        // fv(it) for next iteration's PV
  }
  // --- epilogue: PV for the last chunk ---
  PVphase(sP[(NITER - 1) & 1]);

  // --- unnormalized Y + denom partials ---
  const size_t slot = ((size_t)split * 4 + b) * 128 + qblk;
  if (quad == 0) {
#pragma unroll
    for (int nn = 0; nn < 2; ++nn)
      den[slot * 32 + nn * 16 + q15] = denAcc[nn][0];  // all C rows equal
  }
  float* Yo = Ynum + slot * (64 * 32);
#pragma unroll
  for (int mm = 0; mm < 4; ++mm)
#pragma unroll
    for (int nn = 0; nn < 2; ++nn)
#pragma unroll
      for (int r = 0; r < 4; ++r)
        Yo[(mm * 16 + quad * 4 + r) * 32 + nn * 16 + q15] = Yacc[mm][nn][r];
}

// ---------------------------------------------------------------------------
// Combine the NSPLIT l-splits and normalize. out[b][v][q], 1M elements.
// Ynum [s][b][qblk128][v64][q32], den [s][b][qblk128][q32].
// ---------------------------------------------------------------------------
__global__ __launch_bounds__(256) void combine_kernel(
    const float* __restrict__ Yn, const float* __restrict__ dn,
    float* __restrict__ out) {
  const int idx = blockIdx.x * 256 + threadIdx.x;
  const int q = idx & 4095;
  const int v = (idx >> 12) & 63;
  const int b = idx >> 18;
  const int qb = q >> 5, qq = q & 31;
  float num = 0.f, d = 1e-16f;
#pragma unroll
  for (int s = 0; s < NSPLIT; ++s) {
    const size_t slot = ((size_t)s * 4 + b) * 128 + qb;
    num += Yn[slot * 2048 + v * 32 + qq];
    d += dn[slot * 32 + qq];
  }
  out[idx] = num / d;
}

extern "C" void kernel_launch(void* const* d_in, const int* in_sizes, int n_in,
                              void* d_out, int out_size, void* d_ws,
                              size_t ws_size, hipStream_t stream) {
  const float* field = (const float*)d_in[0];
  const float* query = (const float*)d_in[1];
  const float* Wfk = (const float*)d_in[2];
  const float* bfk = (const float*)d_in[3];
  const float* Wfv = (const float*)d_in[4];
  const float* bfv = (const float*)d_in[5];
  const float* Wqk = (const float*)d_in[6];
  const float* bqk = (const float*)d_in[7];
  float* out = (float*)d_out;

  char* ws = (char*)d_ws;
  u16* fkT = (u16*)(ws);                       // 2 MB   [B][L][64] bf16 (scaled)
  u16* hkT = (u16*)(ws + (2ull << 20));        // 2 MB   [B][L][64] bf16
  u16* fvp = (u16*)(ws + (4ull << 20));        // 2 MB   [B][64][L] bf16
  float* Ynum = (float*)(ws + (6ull << 20));   // 32 MB  [8][B][128qb][64v][32q]
  float* den = (float*)(ws + (38ull << 20));   // 512 KB [8][B][128qb][32q]

  proj_kernel<<<dim3(16, 4, 12), 256, 0, stream>>>(field, query, Wfk, bfk, Wfv,
                                                   bfv, Wqk, bqk, fkT, fvp, hkT);
  attn_kernel<<<dim3(128, 4, NSPLIT), 64, 0, stream>>>(fkT, hkT, fvp, Ynum, den);
  combine_kernel<<<dim3(4096), 256, 0, stream>>>(Ynum, den, out);
}

// Round 7
// 135.266 us; speedup vs baseline: 1.5793x; 1.2705x over previous
//
#include <hip/hip_runtime.h>
#include <hip/hip_bf16.h>

typedef unsigned short u16;
typedef __bf16 bf16x8 __attribute__((ext_vector_type(8)));
typedef __bf16 bf16x4 __attribute__((ext_vector_type(4)));
typedef float f32x4 __attribute__((ext_vector_type(4)));
typedef unsigned int uint32x2 __attribute__((ext_vector_type(2)));

#define MFMA16(a, b, c) __builtin_amdgcn_mfma_f32_16x16x32_bf16(a, b, c, 0, 0, 0)

// exp(z/8) = exp2(z * log2(e)/8); folded into fkF at projection time.
#define FK_SCALE 0.1803368801111204f  // 0.125 * log2(e)

#define NSPLIT 8

// ---------------------------------------------------------------------------
// Projections, writing FRAGMENT-ORDER layouts so attn's loads are contiguous:
//  fkF[b][t=l/16][ks][lane][8]  A-frag order (PRE-SCALED): element (m=l&15,
//     k=ks*32+quad*8+j) at lane=quad*16+m, slot j.  1KB per (t,ks).
//  fvF[b][mm=v/16][cl=l/64][ks][lane][8]: element (m=v&15, k-off=ks*32+
//     quad*8+j -> l=cl*64+koff) at lane=quad*16+m, slot j.
//  hkT[b][q][64]  natural (loaded once per wave).
// grid: (16, B, 12)  z = proj*4 + kquarter (16 k-rows per block).
// ---------------------------------------------------------------------------
__global__ __launch_bounds__(256) void proj_kernel(
    const float* __restrict__ field, const float* __restrict__ query,
    const float* __restrict__ Wfk, const float* __restrict__ bfk,
    const float* __restrict__ Wfv, const float* __restrict__ bfv,
    const float* __restrict__ Wqk, const float* __restrict__ bqk,
    u16* __restrict__ fkF, u16* __restrict__ fvF, u16* __restrict__ hkT) {
  const int l = blockIdx.x * 256 + threadIdx.x;
  const int b = blockIdx.y;
  const int z = blockIdx.z;
  const int proj = z >> 2;        // 0=fk, 1=fv, 2=hk
  const int k0 = (z & 3) * 16;

  const float* src  = (proj == 2) ? query : field;
  const float* W    = (proj == 0) ? Wfk : (proj == 1) ? Wfv : Wqk;
  const float* bias = (proj == 0) ? bfk : (proj == 1) ? bfv : bqk;

  const float* sp = src + (size_t)b * 128 * 4096 + l;

  float acc[16];
#pragma unroll
  for (int i = 0; i < 16; ++i) acc[i] = bias[k0 + i];

  float xc[8];
#pragma unroll
  for (int j = 0; j < 8; ++j) xc[j] = sp[(size_t)j * 4096];

#pragma unroll 1
  for (int fc = 0; fc < 128; fc += 8) {
    float xn[8];
    if (fc + 8 < 128) {
#pragma unroll
      for (int j = 0; j < 8; ++j) xn[j] = sp[(size_t)(fc + 8 + j) * 4096];
    }
#pragma unroll
    for (int i = 0; i < 16; ++i) {
      const float* wr = W + (size_t)(k0 + i) * 128 + fc;
      float a = acc[i];
#pragma unroll
      for (int j = 0; j < 8; ++j) a = fmaf(wr[j], xc[j], a);
      acc[i] = a;
    }
#pragma unroll
    for (int j = 0; j < 8; ++j) xc[j] = xn[j];
  }

  if (proj == 0) {
    // fkF fragment order, scaled
    const int t = l >> 4, m = l & 15;
    const int ks = k0 >> 5, qa = (k0 & 31) >> 3;  // qa in {0,2}
    u16* base = fkF + ((size_t)((b * 256 + t) * 2 + ks)) * 512 + m * 8;
#pragma unroll
    for (int g = 0; g < 2; ++g) {
      bf16x8 o;
#pragma unroll
      for (int j = 0; j < 8; ++j) o[j] = (__bf16)(acc[g * 8 + j] * FK_SCALE);
      *reinterpret_cast<bf16x8*>(base + (qa + g) * 128) = o;
    }
  } else if (proj == 2) {
    u16* dst = hkT + ((size_t)(b * 4096 + l)) * 64 + k0;
#pragma unroll
    for (int g = 0; g < 2; ++g) {
      bf16x8 o;
#pragma unroll
      for (int j = 0; j < 8; ++j) o[j] = (__bf16)acc[g * 8 + j];
      *reinterpret_cast<bf16x8*>(dst + g * 8) = o;
    }
  } else {
    // fvF fragment order: v = k0 + i, mm = z&3
    const int mm = z & 3;
    const int cl = l >> 6, ks = (l & 63) >> 5, quad = (l & 31) >> 3, j = l & 7;
    u16* base = fvF + ((size_t)(((b * 4 + mm) * 64 + cl) * 2 + ks)) * 512 +
                quad * 128 + j;
#pragma unroll
    for (int i = 0; i < 16; ++i) {
      __bf16 h = (__bf16)acc[i];
      base[i * 8] = __builtin_bit_cast(u16, h);
    }
  }
}

// ---------------------------------------------------------------------------
// Attention: barrier-free, cross-chunk pipelined, q-stripe 64 per wave.
// Grid 2048 x 64thr; id -> b = id&3 (XCD-pinned: each XCD sees ONE b ->
// 1.5MB working set, L2-resident), qblk = (id>>2)&63, split = id>>8.
// Per 64-l chunk: S (32 MFMA) -> exp2 -> LDS P (read-order lane-linear,
// dbuf) ; PV of PREVIOUS chunk (40 MFMA incl. ones-MFMA denominator).
// All global fragment loads are contiguous 1KB (fragment-order layouts).
// ---------------------------------------------------------------------------
__global__ __launch_bounds__(64, 2) void attn_kernel(
    const u16* __restrict__ fkF, const u16* __restrict__ hkT,
    const u16* __restrict__ fvF, float* __restrict__ Ynum,
    float* __restrict__ den) {
  constexpr int LL = 4096, DD = 64, CH = 64, NITER = (LL / NSPLIT) / CH;  // 8
  const int lane = threadIdx.x;
  const int q15 = lane & 15;
  const int quad = lane >> 4;
  const int id = blockIdx.x;
  const int b = id & 3;
  const int qblk = (id >> 2) & 63;      // 64 q each
  const int split = id >> 8;
  const int q0 = qblk * 64;
  const int l0base = split * (LL / NSPLIT);

  __shared__ __align__(16) char sP[2][8192];  // P[l64][q64] in read-order

  // hk B-frags, persistent: B[k][n=q], n=q15, k=quad*8+j'
  bf16x8 hkf[4][2];
#pragma unroll
  for (int j = 0; j < 4; ++j)
#pragma unroll
    for (int ks = 0; ks < 2; ++ks)
      hkf[j][ks] = *reinterpret_cast<const bf16x8*>(
          hkT + ((size_t)(b * LL + q0 + j * 16 + q15)) * DD + ks * 32 + quad * 8);

  bf16x8 ones;
#pragma unroll
  for (int j = 0; j < 8; ++j) ones[j] = (__bf16)1.0f;

  f32x4 Yacc[4][4];
#pragma unroll
  for (int mm = 0; mm < 4; ++mm)
#pragma unroll
    for (int nn = 0; nn < 4; ++nn) Yacc[mm][nn] = (f32x4){0.f, 0.f, 0.f, 0.f};
  f32x4 denAcc[4];
#pragma unroll
  for (int nn = 0; nn < 4; ++nn) denAcc[nn] = (f32x4){0.f, 0.f, 0.f, 0.f};

  // write offset inside a (s>>1, jj) 1KB region; read = lane*16 linear
  const int wbase = (quad >> 1) * 256 + q15 * 16 + (quad & 1) * 8;
  const int rbase = lane * 16;

  bf16x8 fkf[4][2];  // A-frags of fk for current chunk (strip s = 16 l)
  bf16x8 af[4][2];   // A-frags of fv for chunk it-1 at PV time

  auto loadFK = [&](int l0) {
    const int t0 = l0 >> 4;
#pragma unroll
    for (int s = 0; s < 4; ++s)
#pragma unroll
      for (int ks = 0; ks < 2; ++ks)
        fkf[s][ks] = *reinterpret_cast<const bf16x8*>(
            fkF + ((size_t)((b * 256 + t0 + s) * 2 + ks)) * 512 + lane * 8);
  };
  auto loadAF = [&](int l0) {
    const int cl = l0 >> 6;
#pragma unroll
    for (int mm = 0; mm < 4; ++mm)
#pragma unroll
      for (int ks = 0; ks < 2; ++ks)
        af[mm][ks] = *reinterpret_cast<const bf16x8*>(
            fvF + ((size_t)(((b * 4 + mm) * 64 + cl) * 2 + ks)) * 512 + lane * 8);
  };
  auto Sphase = [&](char* sPb) {
#pragma unroll
    for (int s = 0; s < 4; ++s) {
      f32x4 accS[4];
#pragma unroll
      for (int jj = 0; jj < 4; ++jj) accS[jj] = (f32x4){0.f, 0.f, 0.f, 0.f};
#pragma unroll
      for (int ks = 0; ks < 2; ++ks)
#pragma unroll
        for (int jj = 0; jj < 4; ++jj)
          accS[jj] = MFMA16(fkf[s][ks], hkf[jj][ks], accS[jj]);
      char* wp = sPb + (s >> 1) * 4096 + (s & 1) * 512 + wbase;
#pragma unroll
      for (int jj = 0; jj < 4; ++jj) {
        bf16x4 pk;
#pragma unroll
        for (int r = 0; r < 4; ++r)
          pk[r] = (__bf16)__builtin_amdgcn_exp2f(accS[jj][r]);
        *reinterpret_cast<uint32x2*>(wp + jj * 1024) =
            __builtin_bit_cast(uint32x2, pk);
      }
    }
  };
  auto PVphase = [&](const char* sPr) {
#pragma unroll
    for (int ks = 0; ks < 2; ++ks) {
      bf16x8 bfr[4];
#pragma unroll
      for (int nn = 0; nn < 4; ++nn)
        bfr[nn] = *reinterpret_cast<const bf16x8*>(
            sPr + ks * 4096 + nn * 1024 + rbase);
#pragma unroll
      for (int nn = 0; nn < 4; ++nn)
        denAcc[nn] = MFMA16(ones, bfr[nn], denAcc[nn]);
#pragma unroll
      for (int mm = 0; mm < 4; ++mm)
#pragma unroll
        for (int nn = 0; nn < 4; ++nn)
          Yacc[mm][nn] = MFMA16(af[mm][ks], bfr[nn], Yacc[mm][nn]);
    }
  };

  // --- prologue ---
  loadFK(l0base);
  loadAF(l0base);
  Sphase(sP[0]);
  loadFK(l0base + CH);

  // --- steady state: PV(it-1) overlaps S(it); loads one chunk ahead ---
#pragma unroll 2
  for (int it = 1; it < NITER; ++it) {
    const int l0 = l0base + it * CH;
    Sphase(sP[it & 1]);
    if (it + 1 < NITER) loadFK(l0 + CH);
    PVphase(sP[(it - 1) & 1]);
    loadAF(l0);
  }
  PVphase(sP[(NITER - 1) & 1]);

  // --- epilogue: fragment-order Ynum (coalesced f32x4) + denom ---
  const size_t slot = ((size_t)split * 4 + b) * 64 + qblk;
  if (quad == 0) {
#pragma unroll
    for (int nn = 0; nn < 4; ++nn)
      den[slot * 64 + nn * 16 + q15] = denAcc[nn][0];  // all C rows equal
  }
  float* Yo = Ynum + slot * 4096;
#pragma unroll
  for (int mm = 0; mm < 4; ++mm)
#pragma unroll
    for (int nn = 0; nn < 4; ++nn)
      *reinterpret_cast<f32x4*>(Yo + (mm * 4 + nn) * 256 + lane * 4) =
          Yacc[mm][nn];
}

// ---------------------------------------------------------------------------
// Combine the NSPLIT l-splits and normalize. out[b][v][q], 1M elements.
// Ynum fragment order: [slot][mm4][nn4][lane64][r4].
// ---------------------------------------------------------------------------
__global__ __launch_bounds__(256) void combine_kernel(
    const float* __restrict__ Yn, const float* __restrict__ dn,
    float* __restrict__ out) {
  const int idx = blockIdx.x * 256 + threadIdx.x;
  const int q = idx & 4095;
  const int v = (idx >> 12) & 63;
  const int b = idx >> 18;
  const int qb = q >> 6;
  const int mm = v >> 4, md = (v >> 2) & 3, r = v & 3;
  const int nn = (q >> 4) & 3, lane = md * 16 + (q & 15);
  float num = 0.f, d = 1e-16f;
#pragma unroll
  for (int s = 0; s < NSPLIT; ++s) {
    const size_t slot = ((size_t)s * 4 + b) * 64 + qb;
    num += Yn[slot * 4096 + (mm * 4 + nn) * 256 + lane * 4 + r];
    d += dn[slot * 64 + (q & 63)];
  }
  out[idx] = num / d;
}

extern "C" void kernel_launch(void* const* d_in, const int* in_sizes, int n_in,
                              void* d_out, int out_size, void* d_ws,
                              size_t ws_size, hipStream_t stream) {
  const float* field = (const float*)d_in[0];
  const float* query = (const float*)d_in[1];
  const float* Wfk = (const float*)d_in[2];
  const float* bfk = (const float*)d_in[3];
  const float* Wfv = (const float*)d_in[4];
  const float* bfv = (const float*)d_in[5];
  const float* Wqk = (const float*)d_in[6];
  const float* bqk = (const float*)d_in[7];
  float* out = (float*)d_out;

  char* ws = (char*)d_ws;
  u16* fkF = (u16*)(ws);                       // 2 MB  frag-order, scaled
  u16* hkT = (u16*)(ws + (2ull << 20));        // 2 MB  natural [b][q][64]
  u16* fvF = (u16*)(ws + (4ull << 20));        // 2 MB  frag-order
  float* Ynum = (float*)(ws + (6ull << 20));   // 32 MB [8*4*64 slots][4096]
  float* den = (float*)(ws + (38ull << 20));   // 512 KB

  proj_kernel<<<dim3(16, 4, 12), 256, 0, stream>>>(field, query, Wfk, bfk, Wfv,
                                                   bfv, Wqk, bqk, fkF, fvF, hkT);
  attn_kernel<<<dim3(2048), 64, 0, stream>>>(fkF, hkT, fvF, Ynum, den);
  combine_kernel<<<dim3(4096), 256, 0, stream>>>(Ynum, den, out);
}